// Round 24
// baseline (780.608 us; speedup 1.0000x reference)
//
#include <hip/hip_runtime.h>

typedef float f32x4 __attribute__((ext_vector_type(4)));
typedef float f32x16 __attribute__((ext_vector_type(16)));
typedef _Float16 f16x8 __attribute__((ext_vector_type(8)));
typedef _Float16 f16x4 __attribute__((ext_vector_type(4)));
typedef _Float16 f16x2 __attribute__((ext_vector_type(2)));

typedef __attribute__((address_space(1))) const unsigned char gbyte;
typedef __attribute__((address_space(3))) unsigned char sbyte;
__device__ __forceinline__ void gload_lds16(const void* gp, void* lp) {
  __builtin_amdgcn_global_load_lds((gbyte*)gp, (sbyte*)lp, 16, 0, 0);
}

// ---------------- 1. weight-pool transpose to [d][o][i], f32 ----------------
__global__ __launch_bounds__(256) void k_wpoolT(const float* __restrict__ gwp,
                                                const float* __restrict__ uwp,
                                                float* __restrict__ wtg,
                                                float* __restrict__ wtu) {
  int idx = blockIdx.x * 256 + threadIdx.x;
  if (idx < 16 * 128 * 128) {
    int d = idx >> 14, rem = idx & 16383, o = rem >> 7, i = rem & 127;
    wtg[idx] = gwp[(d << 14) + (i << 7) + o];          // gwp[d][i][o]
  } else {
    int j = idx - 16 * 128 * 128;
    if (j < 16 * 64 * 128) {
      int d = j >> 13, rem = j & 8191, o = rem >> 7, i = rem & 127;
      wtu[j] = uwp[(d << 13) + (i << 6) + o];          // uwp[d][i][o(64)]
    }
  }
}

// -------- 2. supports = softmax(relu(E E^T)), 4 rows/block (emb reuse) ------
__global__ __launch_bounds__(256) void k_supports(const float* __restrict__ emb,
                                                  _Float16* __restrict__ S) {
  int n0 = blockIdx.x * 4, tid = threadIdx.x;
  __shared__ float e_sh[4][16];
  __shared__ float red[4][4];
  if (tid < 16) {
    int r = tid >> 2, part = tid & 3;
    f32x4 v = *reinterpret_cast<const f32x4*>(emb + (n0 + r) * 16 + part * 4);
    *reinterpret_cast<f32x4*>(&e_sh[r][part * 4]) = v;
  }
  __syncthreads();
  float v[4][16];
  float sum[4] = {0.f, 0.f, 0.f, 0.f};
#pragma unroll
  for (int i = 0; i < 16; i++) {
    int m = i * 256 + tid;
    const f32x4* em = reinterpret_cast<const f32x4*>(emb + m * 16);
    f32x4 e0 = em[0], e1 = em[1], e2 = em[2], e3 = em[3];
#pragma unroll
    for (int r = 0; r < 4; r++) {
      float acc = 0.f;
#pragma unroll
      for (int q = 0; q < 4; q++) acc += e_sh[r][q] * e0[q];
#pragma unroll
      for (int q = 0; q < 4; q++) acc += e_sh[r][4 + q] * e1[q];
#pragma unroll
      for (int q = 0; q < 4; q++) acc += e_sh[r][8 + q] * e2[q];
#pragma unroll
      for (int q = 0; q < 4; q++) acc += e_sh[r][12 + q] * e3[q];
      acc = fmaxf(acc, 0.f);
      float e = __expf(acc);
      v[r][i] = e;
      sum[r] += e;
    }
  }
#pragma unroll
  for (int r = 0; r < 4; r++)
#pragma unroll
    for (int off = 32; off > 0; off >>= 1) sum[r] += __shfl_down(sum[r], off);
  if ((tid & 63) == 0) {
#pragma unroll
    for (int r = 0; r < 4; r++) red[tid >> 6][r] = sum[r];
  }
  __syncthreads();
  float inv[4];
#pragma unroll
  for (int r = 0; r < 4; r++)
    inv[r] = 1.f / (red[0][r] + red[1][r] + red[2][r] + red[3][r]);
#pragma unroll
  for (int i = 0; i < 16; i++)
#pragma unroll
    for (int r = 0; r < 4; r++)
      S[(size_t)(n0 + r) * 4096 + i * 256 + tid] = (_Float16)(v[r][i] * inv[r]);
}

// ------- 3. xs_t[b][c][m] = f16(concat(x,state))  (c-major for GEMM B) ------
__global__ __launch_bounds__(256) void k_concat(const float* __restrict__ x,
                                                const float* __restrict__ st,
                                                _Float16* __restrict__ xs_t) {
  int m0 = blockIdx.x * 64, b = blockIdx.y, tid = threadIdx.x;
  __shared__ __attribute__((aligned(16))) _Float16 T[64][130];
#pragma unroll
  for (int i = 0; i < 16; i++) {
    int li = i * 256 + tid;
    int ml = li >> 6, c = li & 63;
    int base = (b * 4096 + m0 + ml) * 64 + c;
    T[ml][c] = (_Float16)x[base];
    T[ml][64 + c] = (_Float16)st[base];
  }
  __syncthreads();
  int cg = tid >> 3, mch = tid & 7;
#pragma unroll
  for (int cb = 0; cb < 4; cb++) {
    int c = cb * 32 + cg;
    f16x8 tmp;
#pragma unroll
    for (int j = 0; j < 8; j++) tmp[j] = T[mch * 8 + j][c];
    *reinterpret_cast<f16x8*>(&xs_t[(b * 128 + c) * 4096 + m0 + mch * 8]) = tmp;
  }
}

// -------- 4. GEMM1 (256Mx128N, 512 thr; 3-buffer pipeline, counted vmcnt) ---
// T4 mechanism: loads for tile t issued 2 tiles early; per-tile wait is
// vmcnt(6) (allow next tile's 6 loads in flight), NEVER a full drain.
// Raw s_barrier (after the vmcnt) orders buffer reuse: all waves have
// finished compute(t-1) by program order before STAGE(t+2) overwrites
// that buffer. sched_barrier(0) fences per guide rule #18.
__global__ __launch_bounds__(512) void k_gemm(const _Float16* __restrict__ S,
                                              const _Float16* __restrict__ Xt,
                                              _Float16* __restrict__ Y) {
  int nt = blockIdx.x, b = blockIdx.y;
  int tid = threadIdx.x, lane = tid & 63, w = tid >> 6;   // w 0..7
  int wr = w >> 1, wc = w & 1;               // 4 x 2 wave grid
  __shared__ __attribute__((aligned(16))) _Float16 As[3][256 * 64];
  __shared__ __attribute__((aligned(16))) _Float16 Bs[3][128 * 64];
  const _Float16* Sb = S + (size_t)nt * 256 * 4096;
  const _Float16* Xb = Xt + (size_t)b * 128 * 4096;
  f32x16 acc[2][2];
#pragma unroll
  for (int fm = 0; fm < 2; fm++)
#pragma unroll
    for (int fn = 0; fn < 2; fn++)
#pragma unroll
      for (int q = 0; q < 16; q++) acc[fm][fn][q] = 0.f;

  int lrow = lane >> 3;                       // staging row-within-group
  int lcolsw = (((lane & 7) ^ lrow) * 8);     // pre-swizzled source column
  int r32 = lane & 31, hi32 = lane >> 5;
  int swz = (r32 & 7) * 8;                    // read-side XOR (elem units)

  // exactly 6 gloads per wave per tile (4 A + 2 B) -> vmcnt bookkeeping exact
  auto STAGE = [&](int v, int k0) {
#pragma unroll
    for (int i = 0; i < 4; i++) {             // A: 256 rows, 32 j-groups
      int j = w * 4 + i;
      int row = j * 8 + lrow;
      gload_lds16(Sb + (size_t)row * 4096 + k0 + lcolsw, &As[v][j * 512]);
    }
#pragma unroll
    for (int i = 0; i < 2; i++) {             // B: 128 rows, 16 j-groups
      int j = w * 2 + i;
      int row = j * 8 + lrow;
      gload_lds16(Xb + (size_t)row * 4096 + k0 + lcolsw, &Bs[v][j * 512]);
    }
  };

  STAGE(0, 0);
  STAGE(1, 64);
  for (int t = 0; t < 64; ++t) {
    if (t < 63) {
      asm volatile("s_waitcnt vmcnt(6)" ::: "memory");   // tile t landed; t+1 in flight
    } else {
      asm volatile("s_waitcnt vmcnt(0)" ::: "memory");   // final tile
    }
    __builtin_amdgcn_sched_barrier(0);
    __builtin_amdgcn_s_barrier();             // all waves: t landed, t-1 reads done
    __builtin_amdgcn_sched_barrier(0);
    if (t + 2 < 64) STAGE((t + 2) % 3, (t + 2) * 64);
    const _Float16* Av = As[t % 3];
    const _Float16* Bv = Bs[t % 3];
#pragma unroll
    for (int kk = 0; kk < 4; kk++) {
      int col = (kk * 16 + hi32 * 8) ^ swz;
      f16x8 af[2], bf[2];
#pragma unroll
      for (int fm = 0; fm < 2; fm++)
        af[fm] = *reinterpret_cast<const f16x8*>(&Av[(wr * 64 + fm * 32 + r32) * 64 + col]);
#pragma unroll
      for (int fn = 0; fn < 2; fn++)
        bf[fn] = *reinterpret_cast<const f16x8*>(&Bv[(wc * 64 + fn * 32 + r32) * 64 + col]);
#pragma unroll
      for (int fm = 0; fm < 2; fm++)
#pragma unroll
        for (int fn = 0; fn < 2; fn++)
          acc[fm][fn] = __builtin_amdgcn_mfma_f32_32x32x16_f16(af[fm], bf[fn], acc[fm][fn], 0, 0, 0);
    }
  }
#pragma unroll
  for (int fm = 0; fm < 2; fm++)
#pragma unroll
    for (int fn = 0; fn < 2; fn++)
#pragma unroll
      for (int reg = 0; reg < 16; reg++) {
        int row = nt * 256 + wr * 64 + fm * 32 + (reg & 3) + 8 * (reg >> 2) + 4 * hi32;
        int c = wc * 64 + fn * 32 + r32;
        Y[((size_t)row * 64 + b) * 128 + c] = (_Float16)acc[fm][fn][reg];   // [n][b][128]
      }
}

// -------- 4b. GEMM2 (R21-proven half-N, 512 thr; Y [n][b][128]) — CONTROL ---
__global__ __launch_bounds__(512) void k_gemm2(const _Float16* __restrict__ S,
                                               const _Float16* __restrict__ Xt,
                                               _Float16* __restrict__ Y) {
  int nt = blockIdx.x, bp = blockIdx.y;
  int tid = threadIdx.x, lane = tid & 63, w = tid >> 6;
  int wr = w >> 1, wc = w & 1;
  __shared__ __attribute__((aligned(16))) _Float16 As[256 * 64];
  __shared__ __attribute__((aligned(16))) _Float16 Bs[128 * 64];
  const _Float16* Sb = S + (size_t)nt * 256 * 4096;
  const _Float16* Xb = Xt + (size_t)(256 * bp + 64) * 4096;
  f32x16 acc[2][2];
#pragma unroll
  for (int fm = 0; fm < 2; fm++)
#pragma unroll
    for (int fn = 0; fn < 2; fn++)
#pragma unroll
      for (int q = 0; q < 16; q++) acc[fm][fn][q] = 0.f;

  int lrow = lane >> 3;
  int lcolsw = (((lane & 7) ^ lrow) * 8);
  int r32 = lane & 31, hi32 = lane >> 5;
  int swz = (r32 & 7) * 8;
  for (int k0 = 0; k0 < 4096; k0 += 64) {
    __syncthreads();
#pragma unroll
    for (int i = 0; i < 4; i++) {             // A: 256 rows
      int j = w * 4 + i;
      int row = j * 8 + lrow;
      gload_lds16(Sb + (size_t)row * 4096 + k0 + lcolsw, &As[j * 512]);
    }
#pragma unroll
    for (int i = 0; i < 2; i++) {             // B: 128 rows (batch-pair map)
      int j = w * 2 + i;
      int row = j * 8 + lrow;                              // 0..127 tile row
      int groff = ((row >> 6) * 128 + (row & 63)) * 4096;
      gload_lds16(Xb + (size_t)groff + k0 + lcolsw, &Bs[j * 512]);
    }
    __syncthreads();
#pragma unroll
    for (int kk = 0; kk < 4; kk++) {
      int col = (kk * 16 + hi32 * 8) ^ swz;
      f16x8 af[2], bf[2];
#pragma unroll
      for (int fm = 0; fm < 2; fm++)
        af[fm] = *reinterpret_cast<const f16x8*>(&As[(wr * 64 + fm * 32 + r32) * 64 + col]);
#pragma unroll
      for (int fn = 0; fn < 2; fn++)
        bf[fn] = *reinterpret_cast<const f16x8*>(&Bs[(wc * 64 + fn * 32 + r32) * 64 + col]);
#pragma unroll
      for (int fm = 0; fm < 2; fm++)
#pragma unroll
        for (int fn = 0; fn < 2; fn++)
          acc[fm][fn] = __builtin_amdgcn_mfma_f32_32x32x16_f16(af[fm], bf[fn], acc[fm][fn], 0, 0, 0);
    }
  }
#pragma unroll
  for (int fm = 0; fm < 2; fm++)
#pragma unroll
    for (int fn = 0; fn < 2; fn++)
#pragma unroll
      for (int reg = 0; reg < 16; reg++) {
        int row = nt * 256 + wr * 64 + fm * 32 + (reg & 3) + 8 * (reg >> 2) + 4 * hi32;
        int ct = wc * 64 + fn * 32 + r32;       // 0..127 tile col
        int batch = 2 * bp + (ct >> 6);
        int c = 64 + (ct & 63);
        Y[((size_t)row * 64 + batch) * 128 + c] = (_Float16)acc[fm][fn][reg];  // [n][b][128]
      }
}

// ---- 5a. k_wall: W_all[node][o*i] = f16( sum_d E[n0+node][d] * wt[d][o*i] )
__global__ __launch_bounds__(256) void k_wall(const float* __restrict__ emb, int n0,
                                              const float* __restrict__ wt, int OI,
                                              _Float16* __restrict__ Wout) {
  int bx = blockIdx.x, by = blockIdx.y, tid = threadIdx.x;
  __shared__ float e_sh[64][16];
  {
    int node = tid >> 2, part = tid & 3;
    f32x4 v = *reinterpret_cast<const f32x4*>(emb + (n0 + bx * 64 + node) * 16 + part * 4);
    *reinterpret_cast<f32x4*>(&e_sh[node][part * 4]) = v;
  }
  __syncthreads();
  int oi0 = by * 2048 + tid * 8;
#pragma unroll
  for (int g = 0; g < 8; g++) {
    f32x4 a0[8], a1[8];
#pragma unroll
    for (int nn = 0; nn < 8; nn++) { a0[nn] = (f32x4){0,0,0,0}; a1[nn] = (f32x4){0,0,0,0}; }
#pragma unroll
    for (int d = 0; d < 16; d++) {
      const f32x4* p = reinterpret_cast<const f32x4*>(wt + d * OI + oi0);
      f32x4 v0 = p[0], v1 = p[1];
#pragma unroll
      for (int nn = 0; nn < 8; nn++) {
        float e = e_sh[g * 8 + nn][d];
        a0[nn] += e * v0;
        a1[nn] += e * v1;
      }
    }
#pragma unroll
    for (int nn = 0; nn < 8; nn++) {
      f16x8 pk;
#pragma unroll
      for (int q = 0; q < 4; q++) { pk[q] = (_Float16)a0[nn][q]; pk[4 + q] = (_Float16)a1[nn][q]; }
      int node = bx * 64 + g * 8 + nn;                 // chunk-local
      *reinterpret_cast<f16x8*>(Wout + (size_t)node * OI + oi0) = pk;
    }
  }
}

// ---- 5b. gate (MFMA, R15-proven; xg [n][b][128] -> contiguous A) -----------
__global__ __launch_bounds__(256) void k_gate(const _Float16* __restrict__ xg,   // [n][b][128]
                                              const float* __restrict__ emb,
                                              const _Float16* __restrict__ Wc,   // chunk [2048][128][128] (in xs_t)
                                              const float* __restrict__ gbp,
                                              int n0,
                                              _Float16* __restrict__ zb,         // [n][b][64]
                                              _Float16* __restrict__ rb) {       // [n][b][64]
  int n = n0 + blockIdx.x, tid = threadIdx.x, lane = tid & 63, w = tid >> 6;
  __shared__ __attribute__((aligned(16))) _Float16 As[64 * 64];
  __shared__ __attribute__((aligned(16))) _Float16 Bs[128 * 64];
  __shared__ float bias_sh[128];
  const _Float16* wrow = Wc + (size_t)blockIdx.x * 16384;
  const _Float16* arow = xg + (size_t)n * 8192;        // contiguous [b][128]
  if (tid < 128) {
    float s = 0.f;
#pragma unroll
    for (int d = 0; d < 16; d++) s += emb[n * 16 + d] * gbp[d * 128 + tid];
    bias_sh[tid] = s;
  }
  f32x16 acc[2];
#pragma unroll
  for (int fm = 0; fm < 2; fm++)
#pragma unroll
    for (int q = 0; q < 16; q++) acc[fm][q] = 0.f;

  int lrow = lane >> 3;                       // staging row-within-group
  int lcolsw = (((lane & 7) ^ lrow) * 8);     // pre-swizzled source column
  int r32 = lane & 31, hi32 = lane >> 5;
  int swz = (r32 & 7) * 8;                    // read-side XOR (elem units)
  for (int k0 = 0; k0 < 128; k0 += 64) {
    __syncthreads();
#pragma unroll
    for (int i = 0; i < 2; i++) {             // A: 64 rows (b)
      int j = w * 2 + i;
      int row = j * 8 + lrow;
      gload_lds16(arow + row * 128 + k0 + lcolsw, &As[j * 512]);
    }
#pragma unroll
    for (int i = 0; i < 4; i++) {             // B: 128 rows (o)
      int j = w * 4 + i;
      int row = j * 8 + lrow;
      gload_lds16(wrow + row * 128 + k0 + lcolsw, &Bs[j * 512]);
    }
    __syncthreads();
#pragma unroll
    for (int kk = 0; kk < 4; kk++) {
      int col = (kk * 16 + hi32 * 8) ^ swz;
      f16x8 bf = *reinterpret_cast<const f16x8*>(&Bs[(w * 32 + r32) * 64 + col]);
#pragma unroll
      for (int fm = 0; fm < 2; fm++) {
        f16x8 af = *reinterpret_cast<const f16x8*>(&As[(fm * 32 + r32) * 64 + col]);
        acc[fm] = __builtin_amdgcn_mfma_f32_32x32x16_f16(af, bf, acc[fm], 0, 0, 0);
      }
    }
  }
  int o = w * 32 + r32;                       // wave-uniform half: w<2 -> z
  float bias = bias_sh[o];
#pragma unroll
  for (int fm = 0; fm < 2; fm++)
#pragma unroll
    for (int reg = 0; reg < 16; reg++) {
      int brow = fm * 32 + (reg & 3) + 8 * (reg >> 2) + 4 * hi32;
      float val = acc[fm][reg] + bias;
      float sg = 1.f / (1.f + __expf(-val));
      if (o < 64) zb[(n * 64 + brow) * 64 + o] = (_Float16)sg;
      else        rb[(n * 64 + brow) * 64 + (o - 64)] = (_Float16)sg;
    }
}

// ------------- 6. xs_t[b][64+o][m] = f16(z[m][b][o] * state[b][m][o]) -------
__global__ __launch_bounds__(256) void k_cand(const _Float16* __restrict__ zb,
                                              const float* __restrict__ st,
                                              _Float16* __restrict__ xs_t) {
  int m0 = blockIdx.x * 64, b = blockIdx.y, tid = threadIdx.x;
  __shared__ __attribute__((aligned(16))) _Float16 T[64][66];
#pragma unroll
  for (int i = 0; i < 16; i++) {
    int li = i * 256 + tid, ml = li >> 6, o = li & 63;
    float z = (float)zb[((m0 + ml) * 64 + b) * 64 + o];
    float s = st[(b * 4096 + m0 + ml) * 64 + o];
    T[ml][o] = (_Float16)(z * s);
  }
  __syncthreads();
  int og = tid >> 3, mch = tid & 7;
#pragma unroll
  for (int cb = 0; cb < 2; cb++) {
    int o = cb * 32 + og;
    f16x8 tmp;
#pragma unroll
    for (int j = 0; j < 8; j++) tmp[j] = T[mch * 8 + j][o];
    *reinterpret_cast<f16x8*>(&xs_t[(b * 128 + 64 + o) * 4096 + m0 + mch * 8]) = tmp;
  }
}

// ---- 7. update (MFMA, R16-proven; xg [n][b][128], single 4096-node grid) ---
__global__ __launch_bounds__(256) void k_upd(const _Float16* __restrict__ xg2,   // [n][b][128]
                                             const float* __restrict__ emb,
                                             const _Float16* __restrict__ Wc,    // [4096][64][128] (in xs_t)
                                             const float* __restrict__ ubp,
                                             const _Float16* __restrict__ rb,    // [n][b][64]
                                             const float* __restrict__ st,
                                             float* __restrict__ out) {
  int n = blockIdx.x, tid = threadIdx.x, lane = tid & 63, w = tid >> 6;
  int fm = w >> 1, fn = w & 1;
  __shared__ __attribute__((aligned(16))) _Float16 As[64 * 64];
  __shared__ __attribute__((aligned(16))) _Float16 Bs[64 * 64];
  __shared__ float bias_sh[64];
  const _Float16* wrow = Wc + (size_t)n * 8192;
  const _Float16* arow = xg2 + (size_t)n * 8192;       // contiguous [b][128]
  if (tid < 64) {
    float s = 0.f;
#pragma unroll
    for (int d = 0; d < 16; d++) s += emb[n * 16 + d] * ubp[d * 64 + tid];
    bias_sh[tid] = s;
  }
  f32x16 acc;
#pragma unroll
  for (int q = 0; q < 16; q++) acc[q] = 0.f;

  int lrow = lane >> 3;                       // staging row-within-group
  int lcolsw = (((lane & 7) ^ lrow) * 8);     // pre-swizzled source column
  int r32 = lane & 31, hi32 = lane >> 5;
  int swz = (r32 & 7) * 8;                    // read-side XOR (elem units)
  for (int k0 = 0; k0 < 128; k0 += 64) {
    __syncthreads();
#pragma unroll
    for (int i = 0; i < 2; i++) {             // A: 64 rows (b)
      int j = w * 2 + i;
      int row = j * 8 + lrow;
      gload_lds16(arow + row * 128 + k0 + lcolsw, &As[j * 512]);
    }
#pragma unroll
    for (int i = 0; i < 2; i++) {             // B: 64 rows (o)
      int j = w * 2 + i;
      int row = j * 8 + lrow;
      gload_lds16(wrow + row * 128 + k0 + lcolsw, &Bs[j * 512]);
    }
    __syncthreads();
#pragma unroll
    for (int kk = 0; kk < 4; kk++) {
      int col = (kk * 16 + hi32 * 8) ^ swz;
      f16x8 af = *reinterpret_cast<const f16x8*>(&As[(fm * 32 + r32) * 64 + col]);
      f16x8 bf = *reinterpret_cast<const f16x8*>(&Bs[(fn * 32 + r32) * 64 + col]);
      acc = __builtin_amdgcn_mfma_f32_32x32x16_f16(af, bf, acc, 0, 0, 0);
    }
  }
  int o = fn * 32 + r32;
  float bias = bias_sh[o];
#pragma unroll
  for (int reg = 0; reg < 16; reg++) {
    int brow = fm * 32 + (reg & 3) + 8 * (reg >> 2) + 4 * hi32;
    float val = acc[reg] + bias;
    float e2 = __expf(2.f * val);
    float hc = 1.f - 2.f / (e2 + 1.f);        // tanh
    float rr = (float)rb[(n * 64 + brow) * 64 + o];
    float s = st[((size_t)brow * 4096 + n) * 64 + o];
    out[((size_t)brow * 4096 + n) * 64 + o] = rr * s + (1.f - rr) * hc;
  }
}

extern "C" void kernel_launch(void* const* d_in, const int* in_sizes, int n_in,
                              void* d_out, int out_size, void* d_ws, size_t ws_size,
                              hipStream_t stream) {
  const float* x   = (const float*)d_in[0];
  const float* st  = (const float*)d_in[1];
  const float* emb = (const float*)d_in[2];
  const float* gwp = (const float*)d_in[3];
  const float* gbp = (const float*)d_in[4];
  const float* uwp = (const float*)d_in[5];
  const float* ubp = (const float*)d_in[6];
  float* out = (float*)d_out;
  char* ws = (char*)d_ws;

  _Float16* slotA = (_Float16*)(ws + 0);          // S (alive through gemm2)
  _Float16* xs_t  = (_Float16*)(ws + 33554432);   // 67 MB [b][c][m]
  _Float16* xg    = (_Float16*)(ws + 100663296);  // 67 MB [n][b][128]
  _Float16* zb    = (_Float16*)(ws + 167772160);  // 33.5 MB [n][b][64]
  _Float16* rb    = (_Float16*)(ws + 201326592);  // 33.5 MB [n][b][64] (alive to upd)
  float* wtg = (float*)(ws + 234881024);          // 1 MB
  float* wtu = (float*)(ws + 235929600);          // 0.5 MB
  if (ws_size < 236453888ull) return;  // fail loudly rather than corrupt

  k_wpoolT<<<1536, 256, 0, stream>>>(gwp, uwp, wtg, wtu);
  k_supports<<<1024, 256, 0, stream>>>(emb, slotA);
  k_concat<<<dim3(64, 64), 256, 0, stream>>>(x, st, xs_t);
  k_gemm<<<dim3(16, 64), 512, 0, stream>>>(slotA, xs_t, xg);
  // gate in 2 chunks of 2048 nodes; W chunks fill xs_t linearly
  for (int c = 0; c < 2; c++) {
    k_wall<<<dim3(32, 8), 256, 0, stream>>>(emb, c * 2048, wtg, 16384, xs_t);
    k_gate<<<2048, 256, 0, stream>>>(xg, emb, xs_t, gbp, c * 2048, zb, rb);
  }
  k_cand<<<dim3(64, 64), 256, 0, stream>>>(zb, st, xs_t);
  // GEMM2: S still alive in slotA; only the z*state half
  k_gemm2<<<dim3(16, 32), 512, 0, stream>>>(slotA, xs_t, xg);
  // update: ONE chunk of 4096 nodes; W fills all of xs_t (dead after gemm2)
  k_wall<<<dim3(64, 4), 256, 0, stream>>>(emb, 0, wtu, 8192, xs_t);
  k_upd<<<4096, 256, 0, stream>>>(xg, emb, xs_t, ubp, rb, st, out);
}

// Round 25
// 703.394 us; speedup vs baseline: 1.1098x; 1.1098x over previous
//
#include <hip/hip_runtime.h>

typedef float f32x4 __attribute__((ext_vector_type(4)));
typedef float f32x16 __attribute__((ext_vector_type(16)));
typedef _Float16 f16x8 __attribute__((ext_vector_type(8)));
typedef _Float16 f16x4 __attribute__((ext_vector_type(4)));
typedef _Float16 f16x2 __attribute__((ext_vector_type(2)));

typedef __attribute__((address_space(1))) const unsigned char gbyte;
typedef __attribute__((address_space(3))) unsigned char sbyte;
__device__ __forceinline__ void gload_lds16(const void* gp, void* lp) {
  __builtin_amdgcn_global_load_lds((gbyte*)gp, (sbyte*)lp, 16, 0, 0);
}

// ---------------- 1. weight-pool transpose to [d][o][i], f32 ----------------
__global__ __launch_bounds__(256) void k_wpoolT(const float* __restrict__ gwp,
                                                const float* __restrict__ uwp,
                                                float* __restrict__ wtg,
                                                float* __restrict__ wtu) {
  int idx = blockIdx.x * 256 + threadIdx.x;
  if (idx < 16 * 128 * 128) {
    int d = idx >> 14, rem = idx & 16383, o = rem >> 7, i = rem & 127;
    wtg[idx] = gwp[(d << 14) + (i << 7) + o];          // gwp[d][i][o]
  } else {
    int j = idx - 16 * 128 * 128;
    if (j < 16 * 64 * 128) {
      int d = j >> 13, rem = j & 8191, o = rem >> 7, i = rem & 127;
      wtu[j] = uwp[(d << 13) + (i << 6) + o];          // uwp[d][i][o(64)]
    }
  }
}

// -------- 2. supports = softmax(relu(E E^T)), 4 rows/block (emb reuse) ------
__global__ __launch_bounds__(256) void k_supports(const float* __restrict__ emb,
                                                  _Float16* __restrict__ S) {
  int n0 = blockIdx.x * 4, tid = threadIdx.x;
  __shared__ float e_sh[4][16];
  __shared__ float red[4][4];
  if (tid < 16) {
    int r = tid >> 2, part = tid & 3;
    f32x4 v = *reinterpret_cast<const f32x4*>(emb + (n0 + r) * 16 + part * 4);
    *reinterpret_cast<f32x4*>(&e_sh[r][part * 4]) = v;
  }
  __syncthreads();
  float v[4][16];
  float sum[4] = {0.f, 0.f, 0.f, 0.f};
#pragma unroll
  for (int i = 0; i < 16; i++) {
    int m = i * 256 + tid;
    const f32x4* em = reinterpret_cast<const f32x4*>(emb + m * 16);
    f32x4 e0 = em[0], e1 = em[1], e2 = em[2], e3 = em[3];
#pragma unroll
    for (int r = 0; r < 4; r++) {
      float acc = 0.f;
#pragma unroll
      for (int q = 0; q < 4; q++) acc += e_sh[r][q] * e0[q];
#pragma unroll
      for (int q = 0; q < 4; q++) acc += e_sh[r][4 + q] * e1[q];
#pragma unroll
      for (int q = 0; q < 4; q++) acc += e_sh[r][8 + q] * e2[q];
#pragma unroll
      for (int q = 0; q < 4; q++) acc += e_sh[r][12 + q] * e3[q];
      acc = fmaxf(acc, 0.f);
      float e = __expf(acc);
      v[r][i] = e;
      sum[r] += e;
    }
  }
#pragma unroll
  for (int r = 0; r < 4; r++)
#pragma unroll
    for (int off = 32; off > 0; off >>= 1) sum[r] += __shfl_down(sum[r], off);
  if ((tid & 63) == 0) {
#pragma unroll
    for (int r = 0; r < 4; r++) red[tid >> 6][r] = sum[r];
  }
  __syncthreads();
  float inv[4];
#pragma unroll
  for (int r = 0; r < 4; r++)
    inv[r] = 1.f / (red[0][r] + red[1][r] + red[2][r] + red[3][r]);
#pragma unroll
  for (int i = 0; i < 16; i++)
#pragma unroll
    for (int r = 0; r < 4; r++)
      S[(size_t)(n0 + r) * 4096 + i * 256 + tid] = (_Float16)(v[r][i] * inv[r]);
}

// ------- 3. xs_t[b][c][m] = f16(concat(x,state))  (c-major for GEMM B) ------
__global__ __launch_bounds__(256) void k_concat(const float* __restrict__ x,
                                                const float* __restrict__ st,
                                                _Float16* __restrict__ xs_t) {
  int m0 = blockIdx.x * 64, b = blockIdx.y, tid = threadIdx.x;
  __shared__ __attribute__((aligned(16))) _Float16 T[64][130];
#pragma unroll
  for (int i = 0; i < 16; i++) {
    int li = i * 256 + tid;
    int ml = li >> 6, c = li & 63;
    int base = (b * 4096 + m0 + ml) * 64 + c;
    T[ml][c] = (_Float16)x[base];
    T[ml][64 + c] = (_Float16)st[base];
  }
  __syncthreads();
  int cg = tid >> 3, mch = tid & 7;
#pragma unroll
  for (int cb = 0; cb < 4; cb++) {
    int c = cb * 32 + cg;
    f16x8 tmp;
#pragma unroll
    for (int j = 0; j < 8; j++) tmp[j] = T[mch * 8 + j][c];
    *reinterpret_cast<f16x8*>(&xs_t[(b * 128 + c) * 4096 + m0 + mch * 8]) = tmp;
  }
}

// -------- 4. GEMM1 (R20/R21-proven 256Mx128N, 512 thr; Y [n][b][128]) -------
__global__ __launch_bounds__(512) void k_gemm(const _Float16* __restrict__ S,
                                              const _Float16* __restrict__ Xt,
                                              _Float16* __restrict__ Y) {
  int nt = blockIdx.x, b = blockIdx.y;       // x fastest: consecutive share Xb
  int tid = threadIdx.x, lane = tid & 63, w = tid >> 6;   // w 0..7
  int wr = w >> 1, wc = w & 1;               // 4 x 2 wave grid
  __shared__ __attribute__((aligned(16))) _Float16 As[256 * 64];
  __shared__ __attribute__((aligned(16))) _Float16 Bs[128 * 64];
  const _Float16* Sb = S + (size_t)nt * 256 * 4096;
  const _Float16* Xb = Xt + (size_t)b * 128 * 4096;
  f32x16 acc[2][2];
#pragma unroll
  for (int fm = 0; fm < 2; fm++)
#pragma unroll
    for (int fn = 0; fn < 2; fn++)
#pragma unroll
      for (int q = 0; q < 16; q++) acc[fm][fn][q] = 0.f;

  int lrow = lane >> 3;                       // staging row-within-group
  int lcolsw = (((lane & 7) ^ lrow) * 8);     // pre-swizzled source column
  int r32 = lane & 31, hi32 = lane >> 5;
  int swz = (r32 & 7) * 8;                    // read-side XOR (elem units)
  for (int k0 = 0; k0 < 4096; k0 += 64) {
    __syncthreads();
#pragma unroll
    for (int i = 0; i < 4; i++) {             // A: 256 rows, 32 j-groups
      int j = w * 4 + i;
      int row = j * 8 + lrow;
      gload_lds16(Sb + (size_t)row * 4096 + k0 + lcolsw, &As[j * 512]);
    }
#pragma unroll
    for (int i = 0; i < 2; i++) {             // B: 128 rows, 16 j-groups
      int j = w * 2 + i;
      int row = j * 8 + lrow;
      gload_lds16(Xb + (size_t)row * 4096 + k0 + lcolsw, &Bs[j * 512]);
    }
    __syncthreads();
#pragma unroll
    for (int kk = 0; kk < 4; kk++) {
      int col = (kk * 16 + hi32 * 8) ^ swz;
      f16x8 af[2], bf[2];
#pragma unroll
      for (int fm = 0; fm < 2; fm++)
        af[fm] = *reinterpret_cast<const f16x8*>(&As[(wr * 64 + fm * 32 + r32) * 64 + col]);
#pragma unroll
      for (int fn = 0; fn < 2; fn++)
        bf[fn] = *reinterpret_cast<const f16x8*>(&Bs[(wc * 64 + fn * 32 + r32) * 64 + col]);
#pragma unroll
      for (int fm = 0; fm < 2; fm++)
#pragma unroll
        for (int fn = 0; fn < 2; fn++)
          acc[fm][fn] = __builtin_amdgcn_mfma_f32_32x32x16_f16(af[fm], bf[fn], acc[fm][fn], 0, 0, 0);
    }
  }
#pragma unroll
  for (int fm = 0; fm < 2; fm++)
#pragma unroll
    for (int fn = 0; fn < 2; fn++)
#pragma unroll
      for (int reg = 0; reg < 16; reg++) {
        int row = nt * 256 + wr * 64 + fm * 32 + (reg & 3) + 8 * (reg >> 2) + 4 * hi32;
        int c = wc * 64 + fn * 32 + r32;
        Y[((size_t)row * 64 + b) * 128 + c] = (_Float16)acc[fm][fn][reg];   // [n][b][128]
      }
}

// -------- 4b. GEMM2 (R21-proven half-N, 512 thr; Y [n][b][128]) -------------
__global__ __launch_bounds__(512) void k_gemm2(const _Float16* __restrict__ S,
                                               const _Float16* __restrict__ Xt,
                                               _Float16* __restrict__ Y) {
  int nt = blockIdx.x, bp = blockIdx.y;
  int tid = threadIdx.x, lane = tid & 63, w = tid >> 6;
  int wr = w >> 1, wc = w & 1;
  __shared__ __attribute__((aligned(16))) _Float16 As[256 * 64];
  __shared__ __attribute__((aligned(16))) _Float16 Bs[128 * 64];
  const _Float16* Sb = S + (size_t)nt * 256 * 4096;
  const _Float16* Xb = Xt + (size_t)(256 * bp + 64) * 4096;
  f32x16 acc[2][2];
#pragma unroll
  for (int fm = 0; fm < 2; fm++)
#pragma unroll
    for (int fn = 0; fn < 2; fn++)
#pragma unroll
      for (int q = 0; q < 16; q++) acc[fm][fn][q] = 0.f;

  int lrow = lane >> 3;
  int lcolsw = (((lane & 7) ^ lrow) * 8);
  int r32 = lane & 31, hi32 = lane >> 5;
  int swz = (r32 & 7) * 8;
  for (int k0 = 0; k0 < 4096; k0 += 64) {
    __syncthreads();
#pragma unroll
    for (int i = 0; i < 4; i++) {             // A: 256 rows
      int j = w * 4 + i;
      int row = j * 8 + lrow;
      gload_lds16(Sb + (size_t)row * 4096 + k0 + lcolsw, &As[j * 512]);
    }
#pragma unroll
    for (int i = 0; i < 2; i++) {             // B: 128 rows (batch-pair map)
      int j = w * 2 + i;
      int row = j * 8 + lrow;                              // 0..127 tile row
      int groff = ((row >> 6) * 128 + (row & 63)) * 4096;
      gload_lds16(Xb + (size_t)groff + k0 + lcolsw, &Bs[j * 512]);
    }
    __syncthreads();
#pragma unroll
    for (int kk = 0; kk < 4; kk++) {
      int col = (kk * 16 + hi32 * 8) ^ swz;
      f16x8 af[2], bf[2];
#pragma unroll
      for (int fm = 0; fm < 2; fm++)
        af[fm] = *reinterpret_cast<const f16x8*>(&As[(wr * 64 + fm * 32 + r32) * 64 + col]);
#pragma unroll
      for (int fn = 0; fn < 2; fn++)
        bf[fn] = *reinterpret_cast<const f16x8*>(&Bs[(wc * 64 + fn * 32 + r32) * 64 + col]);
#pragma unroll
      for (int fm = 0; fm < 2; fm++)
#pragma unroll
        for (int fn = 0; fn < 2; fn++)
          acc[fm][fn] = __builtin_amdgcn_mfma_f32_32x32x16_f16(af[fm], bf[fn], acc[fm][fn], 0, 0, 0);
    }
  }
#pragma unroll
  for (int fm = 0; fm < 2; fm++)
#pragma unroll
    for (int fn = 0; fn < 2; fn++)
#pragma unroll
      for (int reg = 0; reg < 16; reg++) {
        int row = nt * 256 + wr * 64 + fm * 32 + (reg & 3) + 8 * (reg >> 2) + 4 * hi32;
        int ct = wc * 64 + fn * 32 + r32;       // 0..127 tile col
        int batch = 2 * bp + (ct >> 6);
        int c = 64 + (ct & 63);
        Y[((size_t)row * 64 + batch) * 128 + c] = (_Float16)acc[fm][fn][reg];  // [n][b][128]
      }
}

// ---- 5a. k_wall: W_all[node][o*i] = f16( sum_d E[n0+node][d] * wt[d][o*i] )
__global__ __launch_bounds__(256) void k_wall(const float* __restrict__ emb, int n0,
                                              const float* __restrict__ wt, int OI,
                                              _Float16* __restrict__ Wout) {
  int bx = blockIdx.x, by = blockIdx.y, tid = threadIdx.x;
  __shared__ float e_sh[64][16];
  {
    int node = tid >> 2, part = tid & 3;
    f32x4 v = *reinterpret_cast<const f32x4*>(emb + (n0 + bx * 64 + node) * 16 + part * 4);
    *reinterpret_cast<f32x4*>(&e_sh[node][part * 4]) = v;
  }
  __syncthreads();
  int oi0 = by * 2048 + tid * 8;
#pragma unroll
  for (int g = 0; g < 8; g++) {
    f32x4 a0[8], a1[8];
#pragma unroll
    for (int nn = 0; nn < 8; nn++) { a0[nn] = (f32x4){0,0,0,0}; a1[nn] = (f32x4){0,0,0,0}; }
#pragma unroll
    for (int d = 0; d < 16; d++) {
      const f32x4* p = reinterpret_cast<const f32x4*>(wt + d * OI + oi0);
      f32x4 v0 = p[0], v1 = p[1];
#pragma unroll
      for (int nn = 0; nn < 8; nn++) {
        float e = e_sh[g * 8 + nn][d];
        a0[nn] += e * v0;
        a1[nn] += e * v1;
      }
    }
#pragma unroll
    for (int nn = 0; nn < 8; nn++) {
      f16x8 pk;
#pragma unroll
      for (int q = 0; q < 4; q++) { pk[q] = (_Float16)a0[nn][q]; pk[4 + q] = (_Float16)a1[nn][q]; }
      int node = bx * 64 + g * 8 + nn;                 // chunk-local
      *reinterpret_cast<f16x8*>(Wout + (size_t)node * OI + oi0) = pk;
    }
  }
}

// ---- 5b. gate (MFMA, R15-proven; xg [n][b][128] -> contiguous A) -----------
__global__ __launch_bounds__(256) void k_gate(const _Float16* __restrict__ xg,   // [n][b][128]
                                              const float* __restrict__ emb,
                                              const _Float16* __restrict__ Wc,   // chunk [2048][128][128] (in xs_t)
                                              const float* __restrict__ gbp,
                                              int n0,
                                              _Float16* __restrict__ zb,         // [n][b][64]
                                              _Float16* __restrict__ rb) {       // [n][b][64]
  int n = n0 + blockIdx.x, tid = threadIdx.x, lane = tid & 63, w = tid >> 6;
  __shared__ __attribute__((aligned(16))) _Float16 As[64 * 64];
  __shared__ __attribute__((aligned(16))) _Float16 Bs[128 * 64];
  __shared__ float bias_sh[128];
  const _Float16* wrow = Wc + (size_t)blockIdx.x * 16384;
  const _Float16* arow = xg + (size_t)n * 8192;        // contiguous [b][128]
  if (tid < 128) {
    float s = 0.f;
#pragma unroll
    for (int d = 0; d < 16; d++) s += emb[n * 16 + d] * gbp[d * 128 + tid];
    bias_sh[tid] = s;
  }
  f32x16 acc[2];
#pragma unroll
  for (int fm = 0; fm < 2; fm++)
#pragma unroll
    for (int q = 0; q < 16; q++) acc[fm][q] = 0.f;

  int lrow = lane >> 3;                       // staging row-within-group
  int lcolsw = (((lane & 7) ^ lrow) * 8);     // pre-swizzled source column
  int r32 = lane & 31, hi32 = lane >> 5;
  int swz = (r32 & 7) * 8;                    // read-side XOR (elem units)
  for (int k0 = 0; k0 < 128; k0 += 64) {
    __syncthreads();
#pragma unroll
    for (int i = 0; i < 2; i++) {             // A: 64 rows (b)
      int j = w * 2 + i;
      int row = j * 8 + lrow;
      gload_lds16(arow + row * 128 + k0 + lcolsw, &As[j * 512]);
    }
#pragma unroll
    for (int i = 0; i < 4; i++) {             // B: 128 rows (o)
      int j = w * 4 + i;
      int row = j * 8 + lrow;
      gload_lds16(wrow + row * 128 + k0 + lcolsw, &Bs[j * 512]);
    }
    __syncthreads();
#pragma unroll
    for (int kk = 0; kk < 4; kk++) {
      int col = (kk * 16 + hi32 * 8) ^ swz;
      f16x8 bf = *reinterpret_cast<const f16x8*>(&Bs[(w * 32 + r32) * 64 + col]);
#pragma unroll
      for (int fm = 0; fm < 2; fm++) {
        f16x8 af = *reinterpret_cast<const f16x8*>(&As[(fm * 32 + r32) * 64 + col]);
        acc[fm] = __builtin_amdgcn_mfma_f32_32x32x16_f16(af, bf, acc[fm], 0, 0, 0);
      }
    }
  }
  int o = w * 32 + r32;                       // wave-uniform half: w<2 -> z
  float bias = bias_sh[o];
#pragma unroll
  for (int fm = 0; fm < 2; fm++)
#pragma unroll
    for (int reg = 0; reg < 16; reg++) {
      int brow = fm * 32 + (reg & 3) + 8 * (reg >> 2) + 4 * hi32;
      float val = acc[fm][reg] + bias;
      float sg = 1.f / (1.f + __expf(-val));
      if (o < 64) zb[(n * 64 + brow) * 64 + o] = (_Float16)sg;
      else        rb[(n * 64 + brow) * 64 + (o - 64)] = (_Float16)sg;
    }
}

// ------------- 6. xs_t[b][64+o][m] = f16(z[m][b][o] * state[b][m][o]) -------
__global__ __launch_bounds__(256) void k_cand(const _Float16* __restrict__ zb,
                                              const float* __restrict__ st,
                                              _Float16* __restrict__ xs_t) {
  int m0 = blockIdx.x * 64, b = blockIdx.y, tid = threadIdx.x;
  __shared__ __attribute__((aligned(16))) _Float16 T[64][66];
#pragma unroll
  for (int i = 0; i < 16; i++) {
    int li = i * 256 + tid, ml = li >> 6, o = li & 63;
    float z = (float)zb[((m0 + ml) * 64 + b) * 64 + o];
    float s = st[(b * 4096 + m0 + ml) * 64 + o];
    T[ml][o] = (_Float16)(z * s);
  }
  __syncthreads();
  int og = tid >> 3, mch = tid & 7;
#pragma unroll
  for (int cb = 0; cb < 2; cb++) {
    int o = cb * 32 + og;
    f16x8 tmp;
#pragma unroll
    for (int j = 0; j < 8; j++) tmp[j] = T[mch * 8 + j][o];
    *reinterpret_cast<f16x8*>(&xs_t[(b * 128 + 64 + o) * 4096 + m0 + mch * 8]) = tmp;
  }
}

// ---- 7. update (MFMA, R16-proven; xg [n][b][128], single 4096-node grid) ---
__global__ __launch_bounds__(256) void k_upd(const _Float16* __restrict__ xg2,   // [n][b][128]
                                             const float* __restrict__ emb,
                                             const _Float16* __restrict__ Wc,    // [4096][64][128] (in xs_t)
                                             const float* __restrict__ ubp,
                                             const _Float16* __restrict__ rb,    // [n][b][64]
                                             const float* __restrict__ st,
                                             float* __restrict__ out) {
  int n = blockIdx.x, tid = threadIdx.x, lane = tid & 63, w = tid >> 6;
  int fm = w >> 1, fn = w & 1;
  __shared__ __attribute__((aligned(16))) _Float16 As[64 * 64];
  __shared__ __attribute__((aligned(16))) _Float16 Bs[64 * 64];
  __shared__ float bias_sh[64];
  const _Float16* wrow = Wc + (size_t)n * 8192;
  const _Float16* arow = xg2 + (size_t)n * 8192;       // contiguous [b][128]
  if (tid < 64) {
    float s = 0.f;
#pragma unroll
    for (int d = 0; d < 16; d++) s += emb[n * 16 + d] * ubp[d * 64 + tid];
    bias_sh[tid] = s;
  }
  f32x16 acc;
#pragma unroll
  for (int q = 0; q < 16; q++) acc[q] = 0.f;

  int lrow = lane >> 3;                       // staging row-within-group
  int lcolsw = (((lane & 7) ^ lrow) * 8);     // pre-swizzled source column
  int r32 = lane & 31, hi32 = lane >> 5;
  int swz = (r32 & 7) * 8;                    // read-side XOR (elem units)
  for (int k0 = 0; k0 < 128; k0 += 64) {
    __syncthreads();
#pragma unroll
    for (int i = 0; i < 2; i++) {             // A: 64 rows (b)
      int j = w * 2 + i;
      int row = j * 8 + lrow;
      gload_lds16(arow + row * 128 + k0 + lcolsw, &As[j * 512]);
    }
#pragma unroll
    for (int i = 0; i < 2; i++) {             // B: 64 rows (o)
      int j = w * 2 + i;
      int row = j * 8 + lrow;
      gload_lds16(wrow + row * 128 + k0 + lcolsw, &Bs[j * 512]);
    }
    __syncthreads();
#pragma unroll
    for (int kk = 0; kk < 4; kk++) {
      int col = (kk * 16 + hi32 * 8) ^ swz;
      f16x8 af = *reinterpret_cast<const f16x8*>(&As[(fm * 32 + r32) * 64 + col]);
      f16x8 bf = *reinterpret_cast<const f16x8*>(&Bs[(fn * 32 + r32) * 64 + col]);
      acc = __builtin_amdgcn_mfma_f32_32x32x16_f16(af, bf, acc, 0, 0, 0);
    }
  }
  int o = fn * 32 + r32;
  float bias = bias_sh[o];
#pragma unroll
  for (int reg = 0; reg < 16; reg++) {
    int brow = fm * 32 + (reg & 3) + 8 * (reg >> 2) + 4 * hi32;
    float val = acc[reg] + bias;
    float e2 = __expf(2.f * val);
    float hc = 1.f - 2.f / (e2 + 1.f);        // tanh
    float rr = (float)rb[(n * 64 + brow) * 64 + o];
    float s = st[((size_t)brow * 4096 + n) * 64 + o];
    out[((size_t)brow * 4096 + n) * 64 + o] = rr * s + (1.f - rr) * hc;
  }
}

extern "C" void kernel_launch(void* const* d_in, const int* in_sizes, int n_in,
                              void* d_out, int out_size, void* d_ws, size_t ws_size,
                              hipStream_t stream) {
  const float* x   = (const float*)d_in[0];
  const float* st  = (const float*)d_in[1];
  const float* emb = (const float*)d_in[2];
  const float* gwp = (const float*)d_in[3];
  const float* gbp = (const float*)d_in[4];
  const float* uwp = (const float*)d_in[5];
  const float* ubp = (const float*)d_in[6];
  float* out = (float*)d_out;
  char* ws = (char*)d_ws;

  _Float16* slotA = (_Float16*)(ws + 0);          // S (alive through gemm2)
  _Float16* xs_t  = (_Float16*)(ws + 33554432);   // 67 MB [b][c][m]
  _Float16* xg    = (_Float16*)(ws + 100663296);  // 67 MB [n][b][128]
  _Float16* zb    = (_Float16*)(ws + 167772160);  // 33.5 MB [n][b][64]
  _Float16* rb    = (_Float16*)(ws + 201326592);  // 33.5 MB [n][b][64] (alive to upd)
  float* wtg = (float*)(ws + 234881024);          // 1 MB
  float* wtu = (float*)(ws + 235929600);          // 0.5 MB
  if (ws_size < 236453888ull) return;  // fail loudly rather than corrupt

  k_wpoolT<<<1536, 256, 0, stream>>>(gwp, uwp, wtg, wtu);
  k_supports<<<1024, 256, 0, stream>>>(emb, slotA);
  k_concat<<<dim3(64, 64), 256, 0, stream>>>(x, st, xs_t);
  k_gemm<<<dim3(16, 64), 512, 0, stream>>>(slotA, xs_t, xg);
  // gate in 2 chunks of 2048 nodes; W chunks fill xs_t linearly
  for (int c = 0; c < 2; c++) {
    k_wall<<<dim3(32, 8), 256, 0, stream>>>(emb, c * 2048, wtg, 16384, xs_t);
    k_gate<<<2048, 256, 0, stream>>>(xg, emb, xs_t, gbp, c * 2048, zb, rb);
  }
  k_cand<<<dim3(64, 64), 256, 0, stream>>>(zb, st, xs_t);
  // GEMM2: S still alive in slotA; only the z*state half
  k_gemm2<<<dim3(16, 32), 512, 0, stream>>>(slotA, xs_t, xg);
  // update: ONE chunk of 4096 nodes; W fills all of xs_t (dead after gemm2)
  k_wall<<<dim3(64, 4), 256, 0, stream>>>(emb, 0, wtu, 8192, xs_t);
  k_upd<<<4096, 256, 0, stream>>>(xg, emb, xs_t, ubp, rb, st, out);
}